// Round 7
// baseline (5869.682 us; speedup 1.0000x reference)
//
#include <hip/hip_runtime.h>
#include <hip/hip_bf16.h>
#include <stdint.h>

// B=64 T=64 E=256 S=128 ENC=1024 RNN=1024 ATT=1024 DENSE=8000
// step = 2 dispatches:
//   qattn_k: blocks 0-63 q-GEMM (split-K), blocks 64-575 scores+softmax+ctx,
//            linked by device-scope mailbox (qcnt / scnt / den per (t,b)).
//   gemm_gates: z = [ctx|x|h] @ KRT (gate-permuted) + fused LSTM cell.

typedef __attribute__((ext_vector_type(8))) short short8;
typedef __attribute__((ext_vector_type(4))) float floatx4;
typedef __attribute__((ext_vector_type(4))) unsigned short ushortx4;

__device__ __forceinline__ float b2f(unsigned short u) {
    union { unsigned int i; float f; } v; v.i = ((unsigned int)u) << 16; return v.f;
}
__device__ __forceinline__ unsigned short f2b(float f) {
    union { float f; unsigned int i; } v; v.f = f;
    unsigned int r = v.i + 0x7fffu + ((v.i >> 16) & 1u);
    return (unsigned short)(r >> 16);
}
__device__ __forceinline__ float ftanh(float x) {
    x = fminf(15.f, fmaxf(-15.f, x));
    float e = __expf(2.f * x);
    return (e - 1.f) * __builtin_amdgcn_rcpf(e + 1.f);
}
// branch-free tanh: 1 - 2/(e^{2x}+1)
__device__ __forceinline__ float vtanh(float x) {
    return __builtin_fmaf(-2.f, __builtin_amdgcn_rcpf(__expf(2.f * x) + 1.f), 1.f);
}
__device__ __forceinline__ float fsig(float x) {
    return __builtin_amdgcn_rcpf(1.f + __expf(-x));
}
// async global->LDS, 16B per lane. LDS dest = wave-uniform base + lane*16.
__device__ __forceinline__ void ld_lds16(const void* g, void* l) {
    __builtin_amdgcn_global_load_lds((const __attribute__((address_space(1))) void*)g,
                                     (__attribute__((address_space(3))) void*)l, 16, 0, 0);
}

// ---------------- transpose+convert tile body (shared by prep_all) --------
__device__ __forceinline__ void tr_tile(
    float (*tile)[33], const float* __restrict__ src, int srcld,
    unsigned short* __restrict__ dst, int dstld, int coloff, int perm,
    int bx, int by, int tid)
{
    const int k0 = by * 32, n0 = bx * 32;
    const int r = tid >> 3, c = (tid & 7) * 4;
    int n = n0 + c;
    int cn = perm ? ((((n >> 4) & 3) << 10) | ((n >> 6) << 4) | (n & 15)) : n;
    float4 v = *(const float4*)&src[(size_t)(k0 + r) * srcld + cn];
    tile[r][c + 0] = v.x; tile[r][c + 1] = v.y;
    tile[r][c + 2] = v.z; tile[r][c + 3] = v.w;
    __syncthreads();
    const int nr = tid >> 3, kc = (tid & 7) * 4;
    ushortx4 o;
    o[0] = f2b(tile[kc + 0][nr]);
    o[1] = f2b(tile[kc + 1][nr]);
    o[2] = f2b(tile[kc + 2][nr]);
    o[3] = f2b(tile[kc + 3][nr]);
    *(ushortx4*)&dst[(size_t)(n0 + nr) * dstld + coloff + k0 + kc] = o;
}

// ---------------- one-dispatch prep: transposes + enc conv + init + zero --
// [0,1024) W2 | [1024,2048) W1 | [2048,6144) Wk-ctx | [6144,7168) Wk-x |
// [7168,11264) rk | [11264,19264) Wd | [19264,27456) enc | [27456,27712) h/c
// | [27712,27745) zero mailbox counters
__global__ __launch_bounds__(256) void prep_all(
    const float* __restrict__ W2, unsigned short* __restrict__ W2T,
    const float* __restrict__ W1, unsigned short* __restrict__ W1T,
    const float* __restrict__ Wk, const float* __restrict__ rk,
    unsigned short* __restrict__ KRT,
    const float* __restrict__ Wd, unsigned short* __restrict__ WdT,
    const float* __restrict__ enc, unsigned short* __restrict__ enc_bf,
    const float* __restrict__ hidden, const float* __restrict__ cell,
    float* __restrict__ cb, unsigned short* __restrict__ hbf,
    unsigned int* __restrict__ zt)
{
    __shared__ float tile[32][33];
    const int lid = blockIdx.x, tid = threadIdx.x;
    if (lid < 1024) {
        tr_tile(tile, W2, 1024, W2T, 1024, 0, 0, lid & 31, lid >> 5, tid);
    } else if (lid < 2048) {
        int l = lid - 1024;
        tr_tile(tile, W1, 1024, W1T, 1024, 0, 0, l & 31, l >> 5, tid);
    } else if (lid < 6144) {
        int l = lid - 2048;
        tr_tile(tile, Wk, 4096, KRT, 2304, 0, 1, l & 127, l >> 7, tid);
    } else if (lid < 7168) {
        int l = lid - 6144;
        tr_tile(tile, Wk + 1024 * 4096, 4096, KRT, 2304, 1024, 1, l & 127, l >> 7, tid);
    } else if (lid < 11264) {
        int l = lid - 7168;
        tr_tile(tile, rk, 4096, KRT, 2304, 1280, 1, l & 127, l >> 7, tid);
    } else if (lid < 19264) {
        int l = lid - 11264;
        tr_tile(tile, Wd, 8000, WdT, 1024, 0, 0, l % 250, l / 250, tid);
    } else if (lid < 27456) {
        int i = (lid - 19264) * 256 + tid;
        float4 v = ((const float4*)enc)[i];
        ushortx4 o;
        o[0] = f2b(v.x); o[1] = f2b(v.y); o[2] = f2b(v.z); o[3] = f2b(v.w);
        ((ushortx4*)enc_bf)[i] = o;
    } else if (lid < 27712) {
        int idx = (lid - 27456) * 256 + tid; // < 65536
        float h = hidden[idx], c = cell[idx];
        cb[idx] = c; hbf[idx] = f2b(h);
    } else {
        int i = (lid - 27712) * 256 + tid;   // qcnt(64) + scnt(4096) + den(4096)
        if (i < 8256) zt[i] = 0u;
    }
}

// ---------------- 128x128 MFMA GEMM with global_load_lds (m97-style) ------
// swz!=0: XCD-chunked block remap (8 n-tiles per XCD -> B-panel L2-resident).
__global__ __launch_bounds__(256) void gemm_bf16_128(
    const unsigned short* __restrict__ A, int lda,
    const unsigned short* __restrict__ BT, int ldbt, int K,
    float* __restrict__ Cf, unsigned short* __restrict__ Cb,
    int ldc, int ncols, const float* __restrict__ bias, int swz)
{
    __shared__ __align__(16) unsigned short As[128 * 32];
    __shared__ __align__(16) unsigned short Bs[128 * 32];
    const int tid = threadIdx.x, wave = tid >> 6, lane = tid & 63;
    const int q = lane >> 4, lm = lane & 15;
    const int wr = wave >> 1, wc = wave & 1;
    int bx = blockIdx.x, by = blockIdx.y;
    if (swz) {
        int bid = by * gridDim.x + bx;
        int xcd = bid & 7, l = bid >> 3;
        bx = xcd * 8 + (l & 7);
        by = l >> 3;
    }
    const int m0 = by * 128, n0 = bx * 128;
    const int srow = lane >> 2;
    const int gch = (lane & 3) ^ ((lane >> 3) & 3);
    const unsigned short* Ag0 = A + (size_t)(m0 + wave * 32 + srow) * lda + gch * 8;
    const unsigned short* Ag1 = Ag0 + (size_t)16 * lda;
    const unsigned short* Bg0 = BT + (size_t)(n0 + wave * 32 + srow) * ldbt + gch * 8;
    const unsigned short* Bg1 = Bg0 + (size_t)16 * ldbt;
    unsigned short* Al0 = &As[(wave * 32) * 32];
    unsigned short* Al1 = &As[(wave * 32 + 16) * 32];
    unsigned short* Bl0 = &Bs[(wave * 32) * 32];
    unsigned short* Bl1 = &Bs[(wave * 32 + 16) * 32];

    const floatx4 z4 = {0.f, 0.f, 0.f, 0.f};
    floatx4 acc[4][4];
#pragma unroll
    for (int i = 0; i < 4; i++)
#pragma unroll
        for (int j = 0; j < 4; j++) acc[i][j] = z4;
    const int ach = ((q ^ ((lm >> 1) & 3))) * 8;

    for (int kb = 0; kb < K; kb += 32) {
        ld_lds16(Ag0 + kb, Al0);
        ld_lds16(Ag1 + kb, Al1);
        ld_lds16(Bg0 + kb, Bl0);
        ld_lds16(Bg1 + kb, Bl1);
        __syncthreads();
        short8 a[4], b[4];
#pragma unroll
        for (int i = 0; i < 4; i++) a[i] = *(const short8*)&As[(wr * 64 + i * 16 + lm) * 32 + ach];
#pragma unroll
        for (int j = 0; j < 4; j++) b[j] = *(const short8*)&Bs[(wc * 64 + j * 16 + lm) * 32 + ach];
#pragma unroll
        for (int i = 0; i < 4; i++)
#pragma unroll
            for (int j = 0; j < 4; j++)
                acc[i][j] = __builtin_amdgcn_mfma_f32_16x16x32_bf16(a[i], b[j], acc[i][j], 0, 0, 0);
        __syncthreads();
    }
    const int rb = m0 + wr * 64 + q * 4;
#pragma unroll
    for (int i = 0; i < 4; i++) {
#pragma unroll
        for (int j = 0; j < 4; j++) {
            int col = n0 + wc * 64 + j * 16 + lm;
            if (col < ncols) {
                float bv = bias ? bias[col] : 0.f;
#pragma unroll
                for (int r = 0; r < 4; r++) {
                    float v = acc[i][j][r] + bv;
                    size_t idx = (size_t)(rb + i * 16 + r) * ldc + col;
                    if (Cf) Cf[idx] = v;
                    if (Cb) Cb[idx] = f2b(v);
                }
            }
        }
    }
}

// ------- fused per-step kernel 1: q-GEMM + scores + softmax + ctx ---------
// grid 576 x 256 thr. blocks 0-63: q split-K (bx=blk&15, kz=blk>>4).
// blocks 64-575: (sg, b) = (ab&7, ab>>3); mailbox handoff via qcnt/scnt/den.
__global__ __launch_bounds__(256) void qattn_k(
    const unsigned short* __restrict__ hbf, const unsigned short* __restrict__ W1T,
    float* __restrict__ qp, const float* __restrict__ b1,
    const unsigned short* __restrict__ keys,
    const float* __restrict__ V, const float* __restrict__ bV,
    const unsigned short* __restrict__ enc_bf, const float* __restrict__ x,
    unsigned short* __restrict__ Axc,
    float* __restrict__ esbuf, float* __restrict__ den,
    unsigned int* __restrict__ qcnt, unsigned int* __restrict__ scnt, int t)
{
    __shared__ __align__(16) char smem[33024];
    const int blk = blockIdx.x, tid = threadIdx.x;
    const int wave = tid >> 6, lane = tid & 63;
    const floatx4 z4 = {0.f, 0.f, 0.f, 0.f};

    if (blk < 64) {
        // ----- q partial GEMM: qp[kz][64][1024], cols bx*64..+64 -----
        unsigned short* As = (unsigned short*)smem;            // [4][64*32]
        unsigned short* Bs = (unsigned short*)(smem + 16384);  // [4][64*32]
        const int q = lane >> 4, lm = lane & 15;
        const int bx = blk & 15, kz = blk >> 4;
        const int n0 = bx * 64, k0 = kz * 256;
        const int srow = lane >> 2;
        const int gch = (lane & 3) ^ ((lane >> 3) & 3);
        const unsigned short* Ag = hbf + (size_t)(wave * 16 + srow) * 1024 + k0 + gch * 8;
        const unsigned short* Bg = W1T + (size_t)(n0 + wave * 16 + srow) * 1024 + k0 + gch * 8;
        const int loff = (wave * 16) * 32;
        floatx4 acc0 = z4, acc1 = z4, acc2 = z4, acc3 = z4;
        const int ach = ((q ^ ((lm >> 1) & 3))) * 8;
#pragma unroll
        for (int p = 0; p < 3; ++p) {
            ld_lds16(Ag + p * 32, &As[p * 2048 + loff]);
            ld_lds16(Bg + p * 32, &Bs[p * 2048 + loff]);
        }
#pragma unroll 1
        for (int it = 0; it < 8; ++it) {
            const int st = it & 3;
            if (it < 6)       asm volatile("s_waitcnt vmcnt(4)\n\ts_barrier" ::: "memory");
            else if (it == 6) asm volatile("s_waitcnt vmcnt(2)\n\ts_barrier" ::: "memory");
            else              asm volatile("s_waitcnt vmcnt(0)\n\ts_barrier" ::: "memory");
            if (it + 3 < 8) {
                const int sn = (it + 3) & 3;
                ld_lds16(Ag + (it + 3) * 32, &As[sn * 2048 + loff]);
                ld_lds16(Bg + (it + 3) * 32, &Bs[sn * 2048 + loff]);
            }
            short8 a  = *(const short8*)&As[st * 2048 + (wave * 16 + lm) * 32 + ach];
            short8 b0 = *(const short8*)&Bs[st * 2048 + (0 * 16 + lm) * 32 + ach];
            short8 b1v = *(const short8*)&Bs[st * 2048 + (1 * 16 + lm) * 32 + ach];
            short8 b2 = *(const short8*)&Bs[st * 2048 + (2 * 16 + lm) * 32 + ach];
            short8 b3 = *(const short8*)&Bs[st * 2048 + (3 * 16 + lm) * 32 + ach];
            acc0 = __builtin_amdgcn_mfma_f32_16x16x32_bf16(a, b0, acc0, 0, 0, 0);
            acc1 = __builtin_amdgcn_mfma_f32_16x16x32_bf16(a, b1v, acc1, 0, 0, 0);
            acc2 = __builtin_amdgcn_mfma_f32_16x16x32_bf16(a, b2, acc2, 0, 0, 0);
            acc3 = __builtin_amdgcn_mfma_f32_16x16x32_bf16(a, b3, acc3, 0, 0, 0);
        }
        float* Cp = qp + (size_t)kz * 65536;
        const int rb = wave * 16 + q * 4;
        floatx4 accs[4] = {acc0, acc1, acc2, acc3};
#pragma unroll
        for (int i = 0; i < 4; i++) {
            int col = n0 + i * 16 + lm;
#pragma unroll
            for (int r = 0; r < 4; r++) Cp[(size_t)(rb + r) * 1024 + col] = accs[i][r];
        }
        __syncthreads();   // drains vmcnt(0): all stores complete
        if (tid == 0) {
            __threadfence();
            __hip_atomic_fetch_add(&qcnt[t], 1u, __ATOMIC_RELEASE, __HIP_MEMORY_SCOPE_AGENT);
        }
        return;
    }

    // ----- attn block (sg, b) -----
    const int ab = blk - 64;
    const int sg = ab & 7, b = ab >> 3;
    float* qs    = (float*)smem;            // 1024 f32
    float* vs    = (float*)(smem + 4096);   // 1024 f32
    float* attnv = (float*)(smem + 8192);   // 128 f32
    float* redc  = (float*)(smem + 8704);   // [4][64][2]
    float* misc  = (float*)(smem + 10752);  // [0]=den, [8..24)=es16

    // staging that doesn't need q (overlaps the q-GEMM)
    if (sg == 0 && tid < 128) {   // x_t -> Axc cols 1024..1279
        float x0 = x[((size_t)b * 64 + t) * 256 + tid * 2];
        float x1 = x[((size_t)b * 64 + t) * 256 + tid * 2 + 1];
        ((unsigned int*)&Axc[b * 2304 + 1024])[tid] =
            (unsigned int)f2b(x0) | ((unsigned int)f2b(x1) << 16);
    }
    if (tid < 64) {               // h chunk -> Axc cols 1280+sg*128..
        int c2 = sg * 128 + tid * 2;
        *(unsigned int*)&Axc[b * 2304 + 1280 + c2] =
            *(const unsigned int*)&hbf[b * 1024 + c2];
    }
    {
        float4 av = ((const float4*)V)[tid];
        float4 ab1 = ((const float4*)b1)[tid];
        *(float4*)&vs[tid * 4] = av;
        *(float4*)&qs[tid * 4] = ab1;
    }
    // wait for all 64 q blocks (acquire -> L2 invalidate makes qp visible)
    if (tid == 0) {
        while (__hip_atomic_load(&qcnt[t], __ATOMIC_ACQUIRE, __HIP_MEMORY_SCOPE_AGENT) < 64u)
            __builtin_amdgcn_s_sleep(2);
    }
    __syncthreads();
    {
        float4 r = *(float4*)&qs[tid * 4];
#pragma unroll
        for (int p = 0; p < 4; ++p) {
            float4 a = ((const float4*)(qp + (size_t)p * 65536 + (size_t)b * 1024))[tid];
            r.x += a.x; r.y += a.y; r.z += a.z; r.w += a.w;
        }
        *(float4*)&qs[tid * 4] = r;
    }
    __syncthreads();
    float qr[16], vr[16];
#pragma unroll
    for (int i = 0; i < 4; i++) {
        float4 tq = *(const float4*)&qs[lane * 16 + i * 4];
        float4 tv = *(const float4*)&vs[lane * 16 + i * 4];
        qr[i * 4 + 0] = tq.x; qr[i * 4 + 1] = tq.y; qr[i * 4 + 2] = tq.z; qr[i * 4 + 3] = tq.w;
        vr[i * 4 + 0] = tv.x; vr[i * 4 + 1] = tv.y; vr[i * 4 + 2] = tv.z; vr[i * 4 + 3] = tv.w;
    }
    const float bv0 = bV[0];
    float* es16 = misc + 8;
#pragma unroll
    for (int i = 0; i < 4; i++) {
        const int s = sg * 16 + wave * 4 + i;
        const uint4* kp = (const uint4*)(keys + ((size_t)(b * 128 + s)) * 1024 + lane * 16);
        uint4 k0 = kp[0], k1 = kp[1];
        float kf[16];
        kf[0] = b2f((unsigned short)(k0.x & 0xffff)); kf[1] = b2f((unsigned short)(k0.x >> 16));
        kf[2] = b2f((unsigned short)(k0.y & 0xffff)); kf[3] = b2f((unsigned short)(k0.y >> 16));
        kf[4] = b2f((unsigned short)(k0.z & 0xffff)); kf[5] = b2f((unsigned short)(k0.z >> 16));
        kf[6] = b2f((unsigned short)(k0.w & 0xffff)); kf[7] = b2f((unsigned short)(k0.w >> 16));
        kf[8] = b2f((unsigned short)(k1.x & 0xffff)); kf[9] = b2f((unsigned short)(k1.x >> 16));
        kf[10] = b2f((unsigned short)(k1.y & 0xffff)); kf[11] = b2f((unsigned short)(k1.y >> 16));
        kf[12] = b2f((unsigned short)(k1.z & 0xffff)); kf[13] = b2f((unsigned short)(k1.z >> 16));
        kf[14] = b2f((unsigned short)(k1.w & 0xffff)); kf[15] = b2f((unsigned short)(k1.w >> 16));
        float part = 0.f;
#pragma unroll
        for (int j = 0; j < 16; j++) part += vr[j] * vtanh(qr[j] + kf[j]);
#pragma unroll
        for (int off = 32; off; off >>= 1) part += __shfl_xor(part, off);
        if (lane == 0) es16[wave * 4 + i] = __expf(part + bv0);  // no-max exp (|score|<~16)
    }
    __syncthreads();
    if (tid == 0) {
        float d = 0.f;
#pragma unroll
        for (int k = 0; k < 16; k++) d += es16[k];
        atomicAdd(&den[t * 64 + b], d);
    }
    if (tid < 16) esbuf[b * 128 + sg * 16 + tid] = es16[tid];
    __syncthreads();   // drains stores
    if (tid == 0) {
        __threadfence();
        __hip_atomic_fetch_add(&scnt[t * 64 + b], 1u, __ATOMIC_RELEASE, __HIP_MEMORY_SCOPE_AGENT);
        while (__hip_atomic_load(&scnt[t * 64 + b], __ATOMIC_ACQUIRE, __HIP_MEMORY_SCOPE_AGENT) < 8u)
            __builtin_amdgcn_s_sleep(2);
        misc[0] = __hip_atomic_load(&den[t * 64 + b], __ATOMIC_RELAXED, __HIP_MEMORY_SCOPE_AGENT);
    }
    __syncthreads();
    if (tid < 128) attnv[tid] = esbuf[b * 128 + tid];
    const unsigned int* ep = (const unsigned int*)enc_bf + (size_t)b * 65536 + sg * 64 + lane;
    __syncthreads();
    float ax = 0.f, ay = 0.f;
#pragma unroll 8
    for (int i = 0; i < 32; i++) {
        int s = wave * 32 + i;
        float a = attnv[s];
        unsigned int u = ep[(size_t)s * 512];
        ax += a * b2f((unsigned short)(u & 0xffff));
        ay += a * b2f((unsigned short)(u >> 16));
    }
    redc[(wave * 64 + lane) * 2] = ax; redc[(wave * 64 + lane) * 2 + 1] = ay;
    __syncthreads();
    if (tid < 64) {
        float rs = __builtin_amdgcn_rcpf(misc[0]);
        float fx = (redc[lane * 2] + redc[(64 + lane) * 2] +
                    redc[(128 + lane) * 2] + redc[(192 + lane) * 2]) * rs;
        float fy = (redc[lane * 2 + 1] + redc[(64 + lane) * 2 + 1] +
                    redc[(128 + lane) * 2 + 1] + redc[(192 + lane) * 2 + 1]) * rs;
        *(unsigned int*)&Axc[b * 2304 + sg * 128 + lane * 2] =
            (unsigned int)f2b(fx) | ((unsigned int)f2b(fy) << 16);
    }
}

// ------------- z GEMM (K=2304, in-block split-K x2) + fused LSTM gates -----
__global__ __launch_bounds__(512) void gemm_gates(
    const unsigned short* __restrict__ Axc,
    const unsigned short* __restrict__ KRT,
    const float* __restrict__ bz,
    float* __restrict__ cb,
    unsigned short* __restrict__ hbf, unsigned short* __restrict__ Hall, int t,
    float* __restrict__ out, int last)
{
    __shared__ __align__(16) char smem[65536];
    unsigned short* As = (unsigned short*)smem;             // [4 st][2 h][64*32]
    unsigned short* Bs = (unsigned short*)(smem + 32768);
    float* red = (float*)smem;                              // aliased after loop
    const int tid = threadIdx.x, wave = tid >> 6, lane = tid & 63;
    const int q = lane >> 4, lm = lane & 15;
    const int h = wave >> 2, wm = wave & 3;
    const int bx = blockIdx.x;
    const int srow = lane >> 2;
    const int gch = (lane & 3) ^ ((lane >> 3) & 3);
    const unsigned short* Ag = Axc + (size_t)(wm * 16 + srow) * 2304 + h * 1152 + gch * 8;
    const unsigned short* Bg = KRT + (size_t)(bx * 64 + wm * 16 + srow) * 2304 + h * 1152 + gch * 8;
    const int tileoff = h * 2048;
    const int ldoff = tileoff + (wm * 16) * 32;
    const floatx4 z4 = {0.f, 0.f, 0.f, 0.f};
    floatx4 acc0 = z4, acc1 = z4, acc2 = z4, acc3 = z4;
    const int ach = ((q ^ ((lm >> 1) & 3))) * 8;

#pragma unroll
    for (int p = 0; p < 3; ++p) {
        ld_lds16(Ag + p * 32, &As[p * 4096 + ldoff]);
        ld_lds16(Bg + p * 32, &Bs[p * 4096 + ldoff]);
    }
    for (int it = 0; it < 36; ++it) {
        const int st = it & 3;
        if (it < 34)       asm volatile("s_waitcnt vmcnt(4)\n\ts_barrier" ::: "memory");
        else if (it == 34) asm volatile("s_waitcnt vmcnt(2)\n\ts_barrier" ::: "memory");
        else               asm volatile("s_waitcnt vmcnt(0)\n\ts_barrier" ::: "memory");
        if (it + 3 < 36) {
            const int sn = (it + 3) & 3;
            ld_lds16(Ag + (it + 3) * 32, &As[sn * 4096 + ldoff]);
            ld_lds16(Bg + (it + 3) * 32, &Bs[sn * 4096 + ldoff]);
        }
        const unsigned short* Ast = &As[st * 4096 + tileoff];
        const unsigned short* Bst = &Bs[st * 4096 + tileoff];
        short8 a  = *(const short8*)&Ast[(wm * 16 + lm) * 32 + ach];
        short8 b0 = *(const short8*)&Bst[(0 * 16 + lm) * 32 + ach];
        short8 b1 = *(const short8*)&Bst[(1 * 16 + lm) * 32 + ach];
        short8 b2 = *(const short8*)&Bst[(2 * 16 + lm) * 32 + ach];
        short8 b3 = *(const short8*)&Bst[(3 * 16 + lm) * 32 + ach];
        acc0 = __builtin_amdgcn_mfma_f32_16x16x32_bf16(a, b0, acc0, 0, 0, 0);
        acc1 = __builtin_amdgcn_mfma_f32_16x16x32_bf16(a, b1, acc1, 0, 0, 0);
        acc2 = __builtin_amdgcn_mfma_f32_16x16x32_bf16(a, b2, acc2, 0, 0, 0);
        acc3 = __builtin_amdgcn_mfma_f32_16x16x32_bf16(a, b3, acc3, 0, 0, 0);
    }
    __syncthreads();
    if (h == 1) {
        float* rp = &red[(wm * 64 + lane) * 16];
        *(floatx4*)&rp[0]  = acc0; *(floatx4*)&rp[4]  = acc1;
        *(floatx4*)&rp[8]  = acc2; *(floatx4*)&rp[12] = acc3;
    }
    __syncthreads();
    if (h == 0) {
        const float* rp = &red[(wm * 64 + lane) * 16];
        acc0 += *(const floatx4*)&rp[0];
        acc1 += *(const floatx4*)&rp[4];
        acc2 += *(const floatx4*)&rp[8];
        acc3 += *(const floatx4*)&rp[12];
        const int col = bx * 16 + lm;
        const float bzi = bz[col], bzf = bz[1024 + col];
        const float bzg = bz[2048 + col], bzo = bz[3072 + col];
#pragma unroll
        for (int r = 0; r < 4; ++r) {
            const int b = wm * 16 + q * 4 + r;
            float zi = acc0[r] + bzi;
            float zf = acc1[r] + bzf;
            float zg = acc2[r] + bzg;
            float zo = acc3[r] + bzo;
            float ii = fsig(zi), ff = fsig(zf), gg = ftanh(zg), oo = fsig(zo);
            const int idx = b * 1024 + col;
            float cn = ff * cb[idx] + ii * gg;
            float hn = oo * ftanh(cn);
            cb[idx] = cn;
            unsigned short hb = f2b(hn);
            hbf[idx] = hb;
            Hall[((size_t)b * 64 + t) * 1024 + col] = hb;
            if (last) {
                out[32768000 + idx] = hn;
                out[32768000 + 65536 + idx] = cn;
            }
        }
    }
}

// ---------------------------------------------------------------------------
extern "C" void kernel_launch(void* const* d_in, const int* in_sizes, int n_in,
                              void* d_out, int out_size, void* d_ws, size_t ws_size,
                              hipStream_t stream)
{
    const float* x      = (const float*)d_in[0];   // [64,64,256]
    const float* hidden = (const float*)d_in[1];
    const float* cell   = (const float*)d_in[2];
    const float* enc    = (const float*)d_in[3];   // [64,128,1024]
    const float* W1     = (const float*)d_in[4];   // [1024,1024]
    const float* b1     = (const float*)d_in[5];
    const float* W2     = (const float*)d_in[6];   // [1024,1024]
    const float* b2     = (const float*)d_in[7];
    const float* V      = (const float*)d_in[8];   // [1024]
    const float* bV     = (const float*)d_in[9];
    const float* Wk     = (const float*)d_in[10];  // [1280,4096]
    const float* rk     = (const float*)d_in[11];  // [1024,4096]
    const float* bz     = (const float*)d_in[12];  // [4096]
    const float* Wd     = (const float*)d_in[13];  // [1024,8000]
    const float* bd     = (const float*)d_in[14];  // [8000]
    float* out = (float*)d_out;

    char* ws = (char*)d_ws;
    unsigned short* enc_bf  = (unsigned short*)(ws + 0);          // 16,777,216
    unsigned short* keys_bf = (unsigned short*)(ws + 16777216);   // 16,777,216
    unsigned short* W1T     = (unsigned short*)(ws + 33554432);   //  2,097,152 [1024][1024]
    unsigned short* KRT     = (unsigned short*)(ws + 35651584);   // 18,874,368 [4096][2304] gate-perm
    unsigned short* WdT     = (unsigned short*)(ws + 54525952);   // 16,777,216 [8192][1024]
    unsigned short* Hall    = (unsigned short*)(ws + 71303168);   //  8,388,608 [4096][1024]
    unsigned short* W2T     = Hall;                               // overlap: dead before Hall written
    unsigned short* Axc     = (unsigned short*)(ws + 79691776);   //    294,912 [64][2304]
    float* qp    = (float*)(ws + 79986688);                       //  1,048,576 [4][64][1024]
    unsigned short* hbf     = (unsigned short*)(ws + 81035264);   //    131,072 [64][1024]
    float* esbuf = (float*)(ws + 81166336);                       //     32,768 [64][128]
    float* cb    = (float*)(ws + 81199104);                       //    262,144
    unsigned int* qcnt = (unsigned int*)(ws + 81461248);          //  64 u32
    unsigned int* scnt = qcnt + 64;                               //  4096 u32
    float*        den  = (float*)(scnt + 4096);                   //  4096 f32
    // total 81,494,272 B

    // ---- one-time prep (1 dispatch): transposes + enc conv + init + zero ----
    prep_all<<<27745, 256, 0, stream>>>(W2, W2T, W1, W1T, Wk, rk, KRT, Wd, WdT,
                                        enc, enc_bf, hidden, cell, cb, hbf, qcnt);

    // keys = enc @ W2 + b2 -> bf16 [8192][1024]
    gemm_bf16_128<<<dim3(8, 64), 256, 0, stream>>>(enc_bf, 1024, W2T, 1024, 1024,
                                                   nullptr, keys_bf, 1024, 1024, b2, 0);

    // ---- recurrence (2 kernels/step) ----
    for (int t = 0; t < 64; t++) {
        qattn_k<<<576, 256, 0, stream>>>(hbf, W1T, qp, b1, keys_bf, V, bV,
                                         enc_bf, x, Axc, esbuf, den, qcnt, scnt, t);
        gemm_gates<<<64, 512, 0, stream>>>(Axc, KRT, bz, cb, hbf, Hall, t,
                                           out, (t == 63) ? 1 : 0);
    }

    // logits = Hall @ Wd + bd -> out, XCD-swizzled grid (64 n-tiles, 8/XCD)
    gemm_bf16_128<<<dim3(64, 32), 256, 0, stream>>>(Hall, 1024, WdT, 1024, 1024,
                                                    out, nullptr, 8000, 8000, bd, 1);
}

// Round 8
// 2315.484 us; speedup vs baseline: 2.5350x; 2.5350x over previous
//
#include <hip/hip_runtime.h>
#include <hip/hip_bf16.h>
#include <stdint.h>

// B=64 T=64 E=256 S=128 ENC=1024 RNN=1024 ATT=1024 DENSE=8000
// 4 dispatches/step (structural floor; device-wide sync costs 25-35us, measured):
//   gemm64_split: q partials = h @ W1 (split-K x4)
//   attn_scores : sc[b,s] = V . tanh(q+keys) + bV      (512 blocks)
//   softmax_ctx : ctx (no-max exp, ctx-only) -> Axc[t&1] (512 blocks)
//   gemm_gates  : z = Axc @ KRT (gate-perm) + LSTM; stages x/h -> Axc[(t+1)&1]

typedef __attribute__((ext_vector_type(8))) short short8;
typedef __attribute__((ext_vector_type(4))) float floatx4;
typedef __attribute__((ext_vector_type(4))) unsigned short ushortx4;

__device__ __forceinline__ float b2f(unsigned short u) {
    union { unsigned int i; float f; } v; v.i = ((unsigned int)u) << 16; return v.f;
}
__device__ __forceinline__ unsigned short f2b(float f) {
    union { float f; unsigned int i; } v; v.f = f;
    unsigned int r = v.i + 0x7fffu + ((v.i >> 16) & 1u);
    return (unsigned short)(r >> 16);
}
__device__ __forceinline__ float ftanh(float x) {
    x = fminf(15.f, fmaxf(-15.f, x));
    float e = __expf(2.f * x);
    return (e - 1.f) * __builtin_amdgcn_rcpf(e + 1.f);
}
// branch-free tanh: 1 - 2/(e^{2x}+1)
__device__ __forceinline__ float vtanh(float x) {
    return __builtin_fmaf(-2.f, __builtin_amdgcn_rcpf(__expf(2.f * x) + 1.f), 1.f);
}
__device__ __forceinline__ float fsig(float x) {
    return __builtin_amdgcn_rcpf(1.f + __expf(-x));
}
// async global->LDS, 16B per lane. LDS dest = wave-uniform base + lane*16.
__device__ __forceinline__ void ld_lds16(const void* g, void* l) {
    __builtin_amdgcn_global_load_lds((const __attribute__((address_space(1))) void*)g,
                                     (__attribute__((address_space(3))) void*)l, 16, 0, 0);
}

// ---------------- transpose+convert tile body (shared by prep_all) --------
__device__ __forceinline__ void tr_tile(
    float (*tile)[33], const float* __restrict__ src, int srcld,
    unsigned short* __restrict__ dst, int dstld, int coloff, int perm,
    int bx, int by, int tid)
{
    const int k0 = by * 32, n0 = bx * 32;
    const int r = tid >> 3, c = (tid & 7) * 4;
    int n = n0 + c;
    int cn = perm ? ((((n >> 4) & 3) << 10) | ((n >> 6) << 4) | (n & 15)) : n;
    float4 v = *(const float4*)&src[(size_t)(k0 + r) * srcld + cn];
    tile[r][c + 0] = v.x; tile[r][c + 1] = v.y;
    tile[r][c + 2] = v.z; tile[r][c + 3] = v.w;
    __syncthreads();
    const int nr = tid >> 3, kc = (tid & 7) * 4;
    ushortx4 o;
    o[0] = f2b(tile[kc + 0][nr]);
    o[1] = f2b(tile[kc + 1][nr]);
    o[2] = f2b(tile[kc + 2][nr]);
    o[3] = f2b(tile[kc + 3][nr]);
    *(ushortx4*)&dst[(size_t)(n0 + nr) * dstld + coloff + k0 + kc] = o;
}

// ---------------- one-dispatch prep: transposes + enc conv + init ---------
// [0,1024) W2 | [1024,2048) W1 | [2048,6144) Wk-ctx | [6144,7168) Wk-x |
// [7168,11264) rk | [11264,19264) Wd | [19264,27456) enc | [27456,27712) h/c
// (+h0 -> Axc0) | [27712,27744) x0 -> Axc0
__global__ __launch_bounds__(256) void prep_all(
    const float* __restrict__ W2, unsigned short* __restrict__ W2T,
    const float* __restrict__ W1, unsigned short* __restrict__ W1T,
    const float* __restrict__ Wk, const float* __restrict__ rk,
    unsigned short* __restrict__ KRT,
    const float* __restrict__ Wd, unsigned short* __restrict__ WdT,
    const float* __restrict__ enc, unsigned short* __restrict__ enc_bf,
    const float* __restrict__ hidden, const float* __restrict__ cell,
    const float* __restrict__ x,
    float* __restrict__ cb, unsigned short* __restrict__ hbf,
    unsigned short* __restrict__ Axc0)
{
    __shared__ float tile[32][33];
    const int lid = blockIdx.x, tid = threadIdx.x;
    if (lid < 1024) {
        tr_tile(tile, W2, 1024, W2T, 1024, 0, 0, lid & 31, lid >> 5, tid);
    } else if (lid < 2048) {
        int l = lid - 1024;
        tr_tile(tile, W1, 1024, W1T, 1024, 0, 0, l & 31, l >> 5, tid);
    } else if (lid < 6144) {
        int l = lid - 2048;
        tr_tile(tile, Wk, 4096, KRT, 2304, 0, 1, l & 127, l >> 7, tid);
    } else if (lid < 7168) {
        int l = lid - 6144;
        tr_tile(tile, Wk + 1024 * 4096, 4096, KRT, 2304, 1024, 1, l & 127, l >> 7, tid);
    } else if (lid < 11264) {
        int l = lid - 7168;
        tr_tile(tile, rk, 4096, KRT, 2304, 1280, 1, l & 127, l >> 7, tid);
    } else if (lid < 19264) {
        int l = lid - 11264;
        tr_tile(tile, Wd, 8000, WdT, 1024, 0, 0, l % 250, l / 250, tid);
    } else if (lid < 27456) {
        int i = (lid - 19264) * 256 + tid;
        float4 v = ((const float4*)enc)[i];
        ushortx4 o;
        o[0] = f2b(v.x); o[1] = f2b(v.y); o[2] = f2b(v.z); o[3] = f2b(v.w);
        ((ushortx4*)enc_bf)[i] = o;
    } else if (lid < 27712) {
        int idx = (lid - 27456) * 256 + tid; // < 65536
        float h = hidden[idx], c = cell[idx];
        cb[idx] = c;
        unsigned short hb = f2b(h);
        hbf[idx] = hb;
        Axc0[(idx >> 10) * 2304 + 1280 + (idx & 1023)] = hb;  // h0 -> Axc0
    } else {
        int p = (lid - 27712) * 256 + tid;   // < 8192 packed x0 pairs
        int b = p >> 7, e2 = (p & 127) * 2;
        float x0 = x[((size_t)b * 64) * 256 + e2];
        float x1 = x[((size_t)b * 64) * 256 + e2 + 1];
        *(unsigned int*)&Axc0[b * 2304 + 1024 + e2] =
            (unsigned int)f2b(x0) | ((unsigned int)f2b(x1) << 16);
    }
}

// ---------------- 128x128 MFMA GEMM with global_load_lds (m97-style) ------
// swz=1: logits remap (8 n-tiles per XCD). swz=2: keys remap (8 m-panels/XCD).
__global__ __launch_bounds__(256) void gemm_bf16_128(
    const unsigned short* __restrict__ A, int lda,
    const unsigned short* __restrict__ BT, int ldbt, int K,
    float* __restrict__ Cf, unsigned short* __restrict__ Cb,
    int ldc, int ncols, const float* __restrict__ bias, int swz)
{
    __shared__ __align__(16) unsigned short As[128 * 32];
    __shared__ __align__(16) unsigned short Bs[128 * 32];
    const int tid = threadIdx.x, wave = tid >> 6, lane = tid & 63;
    const int q = lane >> 4, lm = lane & 15;
    const int wr = wave >> 1, wc = wave & 1;
    int bx = blockIdx.x, by = blockIdx.y;
    if (swz == 1) {
        int bid = by * gridDim.x + bx;
        int xcd = bid & 7, l = bid >> 3;
        bx = xcd * 8 + (l & 7);
        by = l >> 3;
    } else if (swz == 2) {
        int bid = by * gridDim.x + bx;
        int xcd = bid & 7, m = bid >> 3;
        by = xcd * 8 + (m & 7);
        bx = m >> 3;
    }
    const int m0 = by * 128, n0 = bx * 128;
    const int srow = lane >> 2;
    const int gch = (lane & 3) ^ ((lane >> 3) & 3);
    const unsigned short* Ag0 = A + (size_t)(m0 + wave * 32 + srow) * lda + gch * 8;
    const unsigned short* Ag1 = Ag0 + (size_t)16 * lda;
    const unsigned short* Bg0 = BT + (size_t)(n0 + wave * 32 + srow) * ldbt + gch * 8;
    const unsigned short* Bg1 = Bg0 + (size_t)16 * ldbt;
    unsigned short* Al0 = &As[(wave * 32) * 32];
    unsigned short* Al1 = &As[(wave * 32 + 16) * 32];
    unsigned short* Bl0 = &Bs[(wave * 32) * 32];
    unsigned short* Bl1 = &Bs[(wave * 32 + 16) * 32];

    const floatx4 z4 = {0.f, 0.f, 0.f, 0.f};
    floatx4 acc[4][4];
#pragma unroll
    for (int i = 0; i < 4; i++)
#pragma unroll
        for (int j = 0; j < 4; j++) acc[i][j] = z4;
    const int ach = ((q ^ ((lm >> 1) & 3))) * 8;

    for (int kb = 0; kb < K; kb += 32) {
        ld_lds16(Ag0 + kb, Al0);
        ld_lds16(Ag1 + kb, Al1);
        ld_lds16(Bg0 + kb, Bl0);
        ld_lds16(Bg1 + kb, Bl1);
        __syncthreads();
        short8 a[4], b[4];
#pragma unroll
        for (int i = 0; i < 4; i++) a[i] = *(const short8*)&As[(wr * 64 + i * 16 + lm) * 32 + ach];
#pragma unroll
        for (int j = 0; j < 4; j++) b[j] = *(const short8*)&Bs[(wc * 64 + j * 16 + lm) * 32 + ach];
#pragma unroll
        for (int i = 0; i < 4; i++)
#pragma unroll
            for (int j = 0; j < 4; j++)
                acc[i][j] = __builtin_amdgcn_mfma_f32_16x16x32_bf16(a[i], b[j], acc[i][j], 0, 0, 0);
        __syncthreads();
    }
    const int rb = m0 + wr * 64 + q * 4;
#pragma unroll
    for (int i = 0; i < 4; i++) {
#pragma unroll
        for (int j = 0; j < 4; j++) {
            int col = n0 + wc * 64 + j * 16 + lm;
            if (col < ncols) {
                float bv = bias ? bias[col] : 0.f;
#pragma unroll
                for (int r = 0; r < 4; r++) {
                    float v = acc[i][j][r] + bv;
                    size_t idx = (size_t)(rb + i * 16 + r) * ldc + col;
                    if (Cf) Cf[idx] = v;
                    if (Cb) Cb[idx] = f2b(v);
                }
            }
        }
    }
}

// ---------------- skinny M=64 GEMM, split-K, f32 partial out --------------
// grid (N/64, 1, SPLIT); Cpart[split][64][ldc]. 4-stage counted-vmcnt pipeline.
__global__ __launch_bounds__(256) void gemm64_split(
    const unsigned short* __restrict__ A, int lda,
    const unsigned short* __restrict__ BT, int ldbt,
    int kchunk, float* __restrict__ Cpart, int ldc)
{
    __shared__ __align__(16) unsigned short As[4][64 * 32];
    __shared__ __align__(16) unsigned short Bs[4][64 * 32];
    const int tid = threadIdx.x, wave = tid >> 6, lane = tid & 63;
    const int q = lane >> 4, lm = lane & 15;
    const int n0 = blockIdx.x * 64;
    const int k0 = blockIdx.z * kchunk;
    const int srow = lane >> 2;
    const int gch = (lane & 3) ^ ((lane >> 3) & 3);
    const unsigned short* Ag = A + (size_t)(wave * 16 + srow) * lda + k0 + gch * 8;
    const unsigned short* Bg = BT + (size_t)(n0 + wave * 16 + srow) * ldbt + k0 + gch * 8;
    const int loff = (wave * 16) * 32;
    const floatx4 z4 = {0.f, 0.f, 0.f, 0.f};
    floatx4 acc0 = z4, acc1 = z4, acc2 = z4, acc3 = z4;
    const int ach = ((q ^ ((lm >> 1) & 3))) * 8;
    const int nit = kchunk >> 5;

#pragma unroll
    for (int p = 0; p < 3; ++p) {
        if (p < nit) {
            ld_lds16(Ag + p * 32, &As[p][loff]);
            ld_lds16(Bg + p * 32, &Bs[p][loff]);
        }
    }
    for (int it = 0; it < nit; ++it) {
        const int st = it & 3;
        if (it + 2 < nit)      asm volatile("s_waitcnt vmcnt(4)\n\ts_barrier" ::: "memory");
        else if (it + 1 < nit) asm volatile("s_waitcnt vmcnt(2)\n\ts_barrier" ::: "memory");
        else                   asm volatile("s_waitcnt vmcnt(0)\n\ts_barrier" ::: "memory");
        if (it + 3 < nit) {
            const int sn = (it + 3) & 3;
            ld_lds16(Ag + (it + 3) * 32, &As[sn][loff]);
            ld_lds16(Bg + (it + 3) * 32, &Bs[sn][loff]);
        }
        short8 a  = *(const short8*)&As[st][(wave * 16 + lm) * 32 + ach];
        short8 b0 = *(const short8*)&Bs[st][(0 * 16 + lm) * 32 + ach];
        short8 b1 = *(const short8*)&Bs[st][(1 * 16 + lm) * 32 + ach];
        short8 b2 = *(const short8*)&Bs[st][(2 * 16 + lm) * 32 + ach];
        short8 b3 = *(const short8*)&Bs[st][(3 * 16 + lm) * 32 + ach];
        acc0 = __builtin_amdgcn_mfma_f32_16x16x32_bf16(a, b0, acc0, 0, 0, 0);
        acc1 = __builtin_amdgcn_mfma_f32_16x16x32_bf16(a, b1, acc1, 0, 0, 0);
        acc2 = __builtin_amdgcn_mfma_f32_16x16x32_bf16(a, b2, acc2, 0, 0, 0);
        acc3 = __builtin_amdgcn_mfma_f32_16x16x32_bf16(a, b3, acc3, 0, 0, 0);
    }
    float* Cp = Cpart + (size_t)blockIdx.z * 64 * ldc;
    const int rb = wave * 16 + q * 4;
    floatx4 accs[4] = {acc0, acc1, acc2, acc3};
#pragma unroll
    for (int i = 0; i < 4; i++) {
        int col = n0 + i * 16 + lm;
#pragma unroll
        for (int r = 0; r < 4; r++) Cp[(size_t)(rb + r) * ldc + col] = accs[i][r];
    }
}

// ------------- scores: sc[b,s] = V . tanh(q[b]+keys[b,s]) + bV ------------
// grid (8, 64): block = (16 s values, b). q = sum of 4 split-K partials + b1.
__global__ __launch_bounds__(256) void attn_scores(
    const float* __restrict__ qp, const float* __restrict__ b1,
    const unsigned short* __restrict__ keys,
    const float* __restrict__ V, const float* __restrict__ bV,
    float* __restrict__ sc)
{
    __shared__ float qs[1024];
    __shared__ float vs[1024];
    const int b = blockIdx.y, sg = blockIdx.x;
    const int tid = threadIdx.x, wave = tid >> 6, lane = tid & 63;
    {
        float4 a0 = ((const float4*)(qp + (size_t)b * 1024))[tid];
        float4 a1 = ((const float4*)(qp + 65536 + (size_t)b * 1024))[tid];
        float4 a2 = ((const float4*)(qp + 131072 + (size_t)b * 1024))[tid];
        float4 a3 = ((const float4*)(qp + 196608 + (size_t)b * 1024))[tid];
        float4 ab = ((const float4*)b1)[tid];
        float4 av = ((const float4*)V)[tid];
        float4 r;
        r.x = a0.x + a1.x + a2.x + a3.x + ab.x;
        r.y = a0.y + a1.y + a2.y + a3.y + ab.y;
        r.z = a0.z + a1.z + a2.z + a3.z + ab.z;
        r.w = a0.w + a1.w + a2.w + a3.w + ab.w;
        *(float4*)&qs[tid * 4] = r;
        *(float4*)&vs[tid * 4] = av;
    }
    __syncthreads();
    float qr[16], vr[16];
#pragma unroll
    for (int i = 0; i < 4; i++) {
        float4 tq = *(const float4*)&qs[lane * 16 + i * 4];
        float4 tv = *(const float4*)&vs[lane * 16 + i * 4];
        qr[i * 4 + 0] = tq.x; qr[i * 4 + 1] = tq.y; qr[i * 4 + 2] = tq.z; qr[i * 4 + 3] = tq.w;
        vr[i * 4 + 0] = tv.x; vr[i * 4 + 1] = tv.y; vr[i * 4 + 2] = tv.z; vr[i * 4 + 3] = tv.w;
    }
    const float bv0 = bV[0];
#pragma unroll
    for (int i = 0; i < 4; i++) {
        const int s = sg * 16 + wave * 4 + i;
        const uint4* kp = (const uint4*)(keys + ((size_t)(b * 128 + s)) * 1024 + lane * 16);
        uint4 k0 = kp[0], k1 = kp[1];
        float kf[16];
        kf[0] = b2f((unsigned short)(k0.x & 0xffff)); kf[1] = b2f((unsigned short)(k0.x >> 16));
        kf[2] = b2f((unsigned short)(k0.y & 0xffff)); kf[3] = b2f((unsigned short)(k0.y >> 16));
        kf[4] = b2f((unsigned short)(k0.z & 0xffff)); kf[5] = b2f((unsigned short)(k0.z >> 16));
        kf[6] = b2f((unsigned short)(k0.w & 0xffff)); kf[7] = b2f((unsigned short)(k0.w >> 16));
        kf[8] = b2f((unsigned short)(k1.x & 0xffff)); kf[9] = b2f((unsigned short)(k1.x >> 16));
        kf[10] = b2f((unsigned short)(k1.y & 0xffff)); kf[11] = b2f((unsigned short)(k1.y >> 16));
        kf[12] = b2f((unsigned short)(k1.z & 0xffff)); kf[13] = b2f((unsigned short)(k1.z >> 16));
        kf[14] = b2f((unsigned short)(k1.w & 0xffff)); kf[15] = b2f((unsigned short)(k1.w >> 16));
        float part = 0.f;
#pragma unroll
        for (int j = 0; j < 16; j++) part += vr[j] * vtanh(qr[j] + kf[j]);
#pragma unroll
        for (int off = 32; off; off >>= 1) part += __shfl_xor(part, off);
        if (lane == 0) sc[b * 128 + s] = part + bv0;
    }
}

// ------ softmax (no-max exp) + ctx -> Axc_t cols 0..1023, bf16 ------------
// grid (8, 64), 256 threads: 128 enc cols/block, s-dim split over 4 waves.
// |score| <= ||V||_1 + |bV| (~16): exp safe without max shift (proven r5).
__global__ __launch_bounds__(256) void softmax_ctx(
    const float* __restrict__ sc, const unsigned short* __restrict__ enc_bf,
    unsigned short* __restrict__ Axc_t)
{
    __shared__ float attnv[128];
    __shared__ float red[4][64][2];
    __shared__ float ssum_s;
    const int b = blockIdx.y, chunk = blockIdx.x;
    const int tid = threadIdx.x, wave = tid >> 6, lane = tid & 63;
    if (tid < 128) attnv[tid] = __expf(sc[b * 128 + tid]);
    __syncthreads();
    if (tid < 64) {
        float s2 = attnv[tid] + attnv[tid + 64];
#pragma unroll
        for (int off = 32; off; off >>= 1) s2 += __shfl_xor(s2, off);
        if (tid == 0) ssum_s = s2;
    }
    const unsigned int* ep = (const unsigned int*)enc_bf + (size_t)b * 65536 + chunk * 64 + lane;
    __syncthreads();
    float ax = 0.f, ay = 0.f;
#pragma unroll 8
    for (int i = 0; i < 32; i++) {
        int s = wave * 32 + i;
        float a = attnv[s];
        unsigned int u = ep[(size_t)s * 512];
        ax += a * b2f((unsigned short)(u & 0xffff));
        ay += a * b2f((unsigned short)(u >> 16));
    }
    red[wave][lane][0] = ax; red[wave][lane][1] = ay;
    __syncthreads();
    if (tid < 64) {
        float rs = __builtin_amdgcn_rcpf(ssum_s);
        float fx = (red[0][lane][0] + red[1][lane][0] + red[2][lane][0] + red[3][lane][0]) * rs;
        float fy = (red[0][lane][1] + red[1][lane][1] + red[2][lane][1] + red[3][lane][1]) * rs;
        *(unsigned int*)&Axc_t[b * 2304 + chunk * 128 + lane * 2] =
            (unsigned int)f2b(fx) | ((unsigned int)f2b(fy) << 16);
    }
}

// ------------- z GEMM (K=2304, in-block split-K x2) + fused LSTM gates -----
// Reads Axc_r (= Axc[t&1]); stages x_{t+1} (h==1 waves) and h_{t+1} (epilogue)
// into Axc_w (= Axc[(t+1)&1]) -- no race: K-loop never touches Axc_w.
__global__ __launch_bounds__(512) void gemm_gates(
    const unsigned short* __restrict__ Axc_r,
    unsigned short* __restrict__ Axc_w,
    const unsigned short* __restrict__ KRT,
    const float* __restrict__ bz,
    float* __restrict__ cb,
    unsigned short* __restrict__ hbf, unsigned short* __restrict__ Hall,
    const float* __restrict__ x, int t,
    float* __restrict__ out, int last)
{
    __shared__ __align__(16) char smem[65536];
    unsigned short* As = (unsigned short*)smem;             // [4 st][2 h][64*32]
    unsigned short* Bs = (unsigned short*)(smem + 32768);
    float* red = (float*)smem;                              // aliased after loop
    const int tid = threadIdx.x, wave = tid >> 6, lane = tid & 63;
    const int q = lane >> 4, lm = lane & 15;
    const int h = wave >> 2, wm = wave & 3;
    const int bx = blockIdx.x;
    const int srow = lane >> 2;
    const int gch = (lane & 3) ^ ((lane >> 3) & 3);
    const unsigned short* Ag = Axc_r + (size_t)(wm * 16 + srow) * 2304 + h * 1152 + gch * 8;
    const unsigned short* Bg = KRT + (size_t)(bx * 64 + wm * 16 + srow) * 2304 + h * 1152 + gch * 8;
    const int tileoff = h * 2048;
    const int ldoff = tileoff + (wm * 16) * 32;
    const floatx4 z4 = {0.f, 0.f, 0.f, 0.f};
    floatx4 acc0 = z4, acc1 = z4, acc2 = z4, acc3 = z4;
    const int ach = ((q ^ ((lm >> 1) & 3))) * 8;

#pragma unroll
    for (int p = 0; p < 3; ++p) {
        ld_lds16(Ag + p * 32, &As[p * 4096 + ldoff]);
        ld_lds16(Bg + p * 32, &Bs[p * 4096 + ldoff]);
    }
    for (int it = 0; it < 36; ++it) {
        const int st = it & 3;
        if (it < 34)       asm volatile("s_waitcnt vmcnt(4)\n\ts_barrier" ::: "memory");
        else if (it == 34) asm volatile("s_waitcnt vmcnt(2)\n\ts_barrier" ::: "memory");
        else               asm volatile("s_waitcnt vmcnt(0)\n\ts_barrier" ::: "memory");
        if (it + 3 < 36) {
            const int sn = (it + 3) & 3;
            ld_lds16(Ag + (it + 3) * 32, &As[sn * 4096 + ldoff]);
            ld_lds16(Bg + (it + 3) * 32, &Bs[sn * 4096 + ldoff]);
        }
        const unsigned short* Ast = &As[st * 4096 + tileoff];
        const unsigned short* Bst = &Bs[st * 4096 + tileoff];
        short8 a  = *(const short8*)&Ast[(wm * 16 + lm) * 32 + ach];
        short8 b0 = *(const short8*)&Bst[(0 * 16 + lm) * 32 + ach];
        short8 b1 = *(const short8*)&Bst[(1 * 16 + lm) * 32 + ach];
        short8 b2 = *(const short8*)&Bst[(2 * 16 + lm) * 32 + ach];
        short8 b3 = *(const short8*)&Bst[(3 * 16 + lm) * 32 + ach];
        acc0 = __builtin_amdgcn_mfma_f32_16x16x32_bf16(a, b0, acc0, 0, 0, 0);
        acc1 = __builtin_amdgcn_mfma_f32_16x16x32_bf16(a, b1, acc1, 0, 0, 0);
        acc2 = __builtin_amdgcn_mfma_f32_16x16x32_bf16(a, b2, acc2, 0, 0, 0);
        acc3 = __builtin_amdgcn_mfma_f32_16x16x32_bf16(a, b3, acc3, 0, 0, 0);
    }
    __syncthreads();
    if (h == 1) {
        float* rp = &red[(wm * 64 + lane) * 16];
        *(floatx4*)&rp[0]  = acc0; *(floatx4*)&rp[4]  = acc1;
        *(floatx4*)&rp[8]  = acc2; *(floatx4*)&rp[12] = acc3;
        // stage x_{t+1} for block's b=bx (idle waves)
        if (t < 63) {
            int local = tid - 256;
            if (local < 128) {
                const float* xp = x + ((size_t)bx * 64 + t + 1) * 256 + local * 2;
                float x0 = xp[0], x1 = xp[1];
                ((unsigned int*)&Axc_w[bx * 2304 + 1024])[local] =
                    (unsigned int)f2b(x0) | ((unsigned int)f2b(x1) << 16);
            }
        }
    }
    __syncthreads();
    if (h == 0) {
        const float* rp = &red[(wm * 64 + lane) * 16];
        acc0 += *(const floatx4*)&rp[0];
        acc1 += *(const floatx4*)&rp[4];
        acc2 += *(const floatx4*)&rp[8];
        acc3 += *(const floatx4*)&rp[12];
        const int col = bx * 16 + lm;
        const float bzi = bz[col], bzf = bz[1024 + col];
        const float bzg = bz[2048 + col], bzo = bz[3072 + col];
#pragma unroll
        for (int r = 0; r < 4; ++r) {
            const int b = wm * 16 + q * 4 + r;
            float zi = acc0[r] + bzi;
            float zf = acc1[r] + bzf;
            float zg = acc2[r] + bzg;
            float zo = acc3[r] + bzo;
            float ii = fsig(zi), ff = fsig(zf), gg = ftanh(zg), oo = fsig(zo);
            const int idx = b * 1024 + col;
            float cn = ff * cb[idx] + ii * gg;
            float hn = oo * ftanh(cn);
            cb[idx] = cn;
            unsigned short hb = f2b(hn);
            hbf[idx] = hb;
            Hall[((size_t)b * 64 + t) * 1024 + col] = hb;
            if (t < 63) Axc_w[b * 2304 + 1280 + col] = hb;  // h_{t+1} stage
            if (last) {
                out[32768000 + idx] = hn;
                out[32768000 + 65536 + idx] = cn;
            }
        }
    }
}

// ---------------------------------------------------------------------------
extern "C" void kernel_launch(void* const* d_in, const int* in_sizes, int n_in,
                              void* d_out, int out_size, void* d_ws, size_t ws_size,
                              hipStream_t stream)
{
    const float* x      = (const float*)d_in[0];   // [64,64,256]
    const float* hidden = (const float*)d_in[1];
    const float* cell   = (const float*)d_in[2];
    const float* enc    = (const float*)d_in[3];   // [64,128,1024]
    const float* W1     = (const float*)d_in[4];   // [1024,1024]
    const float* b1     = (const float*)d_in[5];
    const float* W2     = (const float*)d_in[6];   // [1024,1024]
    const float* b2     = (const float*)d_in[7];
    const float* V      = (const float*)d_in[8];   // [1024]
    const float* bV     = (const float*)d_in[9];
    const float* Wk     = (const float*)d_in[10];  // [1280,4096]
    const float* rk     = (const float*)d_in[11];  // [1024,4096]
    const float* bz     = (const float*)d_in[12];  // [4096]
    const float* Wd     = (const float*)d_in[13];  // [1024,8000]
    const float* bd     = (const float*)d_in[14];  // [8000]
    float* out = (float*)d_out;

    char* ws = (char*)d_ws;
    unsigned short* enc_bf  = (unsigned short*)(ws + 0);          // 16,777,216
    unsigned short* keys_bf = (unsigned short*)(ws + 16777216);   // 16,777,216
    unsigned short* W1T     = (unsigned short*)(ws + 33554432);   //  2,097,152 [1024][1024]
    unsigned short* KRT     = (unsigned short*)(ws + 35651584);   // 18,874,368 [4096][2304] gate-perm
    unsigned short* WdT     = (unsigned short*)(ws + 54525952);   // 16,777,216 [8192][1024]
    unsigned short* Hall    = (unsigned short*)(ws + 71303168);   //  8,388,608 [4096][1024]
    unsigned short* W2T     = Hall;                               // overlap: dead before Hall written
    unsigned short* Axc     = (unsigned short*)(ws + 79691776);   //    589,824 [2][64][2304]
    float* qp    = (float*)(ws + 80281600);                       //  1,048,576 [4][64][1024]
    unsigned short* hbf     = (unsigned short*)(ws + 81330176);   //    131,072 [64][1024]
    float* scbuf = (float*)(ws + 81461248);                       //     32,768 [64][128]
    float* cb    = (float*)(ws + 81494016);                       //    262,144
    // total 81,756,160 B

    // ---- one-time prep (1 dispatch) ----
    prep_all<<<27744, 256, 0, stream>>>(W2, W2T, W1, W1T, Wk, rk, KRT, Wd, WdT,
                                        enc, enc_bf, hidden, cell, x, cb, hbf, Axc);

    // keys = enc @ W2 + b2 -> bf16 [8192][1024]; XCD m-panel swizzle
    gemm_bf16_128<<<dim3(8, 64), 256, 0, stream>>>(enc_bf, 1024, W2T, 1024, 1024,
                                                   nullptr, keys_bf, 1024, 1024, b2, 2);

    // ---- recurrence (4 kernels/step; structural floor) ----
    for (int t = 0; t < 64; t++) {
        unsigned short* Axc_r = Axc + (size_t)(t & 1) * 147456;
        unsigned short* Axc_w = Axc + (size_t)((t + 1) & 1) * 147456;
        gemm64_split<<<dim3(16, 1, 4), 256, 0, stream>>>(hbf, 1024, W1T, 1024, 256, qp, 1024);
        attn_scores<<<dim3(8, 64), 256, 0, stream>>>(qp, b1, keys_bf, V, bV, scbuf);
        softmax_ctx<<<dim3(8, 64), 256, 0, stream>>>(scbuf, enc_bf, Axc_r);
        gemm_gates<<<64, 512, 0, stream>>>(Axc_r, Axc_w, KRT, bz, cb, hbf, Hall,
                                           x, t, out, (t == 63) ? 1 : 0);
    }

    // logits = Hall @ Wd + bd -> out, XCD-swizzled grid (64 n-tiles, 8/XCD)
    gemm_bf16_128<<<dim3(64, 32), 256, 0, stream>>>(Hall, 1024, WdT, 1024, 1024,
                                                    out, nullptr, 8000, 8000, bd, 1);
}